// Round 7
// baseline (109.856 us; speedup 1.0000x reference)
//
#include <hip/hip_runtime.h>

// PointsRenderer: B=4, N=100000, F=64, S=256, K=8, R=2/256
// out = (B, F+1, S, S) f32: channels 0..63 = composited features, 64 = depth.
//
// Rounds 1-6 characterization: all structural variants converge to ~92 us /
// ~3.6 TB/s effective on the random-row-gather mix (HBM 43%, VALU 21%, LDS 0
// conflicts). Nulls: VALU shape, gather width, MLP, nt aux/writes, occupancy,
// fp16 (net negative with its convert prologue). This round's single
// variable: non-temporal GATHER loads (no L1 allocation) to test the per-CU
// L1 miss-queue-ceiling hypothesis (64 misses x 64B / ~700cy x 256CU = 3.6 TB/s).

#define BB 4
#define NN 100000
#define FF 64
#define SS 256
#define KK 8
#define BN (BB * NN)          // 400000
#define RR_INV 16384.0f       // 1 / (r*r),  r = 2*1.0/256

typedef float f32x4 __attribute__((ext_vector_type(4)));
typedef int   i32x4 __attribute__((ext_vector_type(4)));

__global__ __launch_bounds__(256)
void points_render_kernel(const float* __restrict__ features, // [BN][FF]
                          const int*   __restrict__ idx,      // [B][S][S][K] int32
                          const float* __restrict__ zbuf,     // [B][S][S][K]
                          const float* __restrict__ dist,     // [B][S][S][K]
                          float* __restrict__ out)            // [B][FF+1][S][S]
{
    // Block covers 64 consecutive x-pixels of one row (b, y).
    __shared__ float tile[64][FF + 1];      // [local x][channel], stride 65
    __shared__ float s_contrib[64][KK];     // per-(pixel,k) compositing weight
    __shared__ int   s_off[64][KK];         // pre-scaled gather offset si*FF

    const int tid  = threadIdx.x;
    const int wave = tid >> 6;
    const int lane = tid & 63;

    const int blk = blockIdx.x;             // 4096 blocks
    const int xb  = blk & 3;
    const int y   = (blk >> 2) & (SS - 1);
    const int b   = blk >> 10;
    const int x0  = xb * 64;

    const long long pixbase = (((long long)b * SS + y) * SS + x0);

    // ---- Phase A: all 4 waves; lanes 0..15 of wave w own pixels w*16.. ----
    if (lane < 16) {
        const int pix = wave * 16 + lane;
        const long long p = pixbase + pix;
        const f32x4* d4 = (const f32x4*)(dist + p * KK);
        const f32x4* z4 = (const f32x4*)(zbuf + p * KK);
        const i32x4* i4 = (const i32x4*)(idx  + p * KK);
        const f32x4 da = __builtin_nontemporal_load(d4);
        const f32x4 db = __builtin_nontemporal_load(d4 + 1);
        const f32x4 za = __builtin_nontemporal_load(z4);
        const f32x4 zb = __builtin_nontemporal_load(z4 + 1);
        const i32x4 ia = __builtin_nontemporal_load(i4);
        const i32x4 ib = __builtin_nontemporal_load(i4 + 1);

        float dd[KK] = {da.x, da.y, da.z, da.w, db.x, db.y, db.z, db.w};
        float zz[KK] = {za.x, za.y, za.z, za.w, zb.x, zb.y, zb.z, zb.w};
        int   ii[KK] = {ia.x, ia.y, ia.z, ia.w, ib.x, ib.y, ib.z, ib.w};

        float trans = 1.0f, wsum = 0.0f, depth = 0.0f;
        #pragma unroll
        for (int k = 0; k < KK; ++k) {
            float a  = __expf(-fmaxf(dd[k] * RR_INV, 0.0f));
            float we = fminf(a, 0.99f);
            if (ii[k] < 0) we = 0.0f;                 // valid mask
            s_contrib[pix][k] = we * trans;
            trans *= (1.0f - we);
            wsum  += we;
            depth += zz[k] * we;

            int si = ii[k];
            si = si < 0 ? 0 : (si > BN - 1 ? BN - 1 : si);  // safe_idx
            s_off[pix][k] = si * FF;
        }
        tile[pix][FF] = depth / fmaxf(wsum, 1e-9f);
    }
    __syncthreads();

    // ---- Phase B: gather + FMA. Wave w owns pixels [w*16, w*16+16).
    //      lane = feature index. THIS ROUND: gathers are non-temporal
    //      (no L1 allocation) to probe the L1 miss-path ceiling. ----
    const float* fl = features + lane;     // per-lane column base

    #pragma unroll 4
    for (int i = 0; i < 16; ++i) {
        const int xl = wave * 16 + i;
        // wave-uniform LDS broadcasts (no conflicts)
        const float4 c0 = *(const float4*)&s_contrib[xl][0];
        const float4 c1 = *(const float4*)&s_contrib[xl][4];
        const int4   o0 = *(const int4*)&s_off[xl][0];
        const int4   o1 = *(const int4*)&s_off[xl][4];

        // 8 coalesced 256B gathers, streaming (no L1 alloc)
        const float g0 = __builtin_nontemporal_load(fl + o0.x);
        const float g1 = __builtin_nontemporal_load(fl + o0.y);
        const float g2 = __builtin_nontemporal_load(fl + o0.z);
        const float g3 = __builtin_nontemporal_load(fl + o0.w);
        const float g4 = __builtin_nontemporal_load(fl + o1.x);
        const float g5 = __builtin_nontemporal_load(fl + o1.y);
        const float g6 = __builtin_nontemporal_load(fl + o1.z);
        const float g7 = __builtin_nontemporal_load(fl + o1.w);

        tile[xl][lane] = g0*c0.x + g1*c0.y + g2*c0.z + g3*c0.w
                       + g4*c1.x + g5*c1.y + g6*c1.z + g7*c1.w;
    }
    __syncthreads();

    // ---- Write 64 x 65 floats: contiguous 256B channel segments ----
    float* outb = out + (long long)b * (FF + 1) * SS * SS + (long long)y * SS + x0;
    for (int j = tid; j < 64 * (FF + 1); j += 256) {
        const int c  = j >> 6;
        const int xl = j & 63;
        __builtin_nontemporal_store(tile[xl][c], &outb[(long long)c * (SS * SS) + xl]);
    }
}

extern "C" void kernel_launch(void* const* d_in, const int* in_sizes, int n_in,
                              void* d_out, int out_size, void* d_ws, size_t ws_size,
                              hipStream_t stream) {
    const float* features = (const float*)d_in[0];
    const int*   idx      = (const int*)d_in[1];
    const float* zbuf     = (const float*)d_in[2];
    const float* dist     = (const float*)d_in[3];
    float* out = (float*)d_out;

    const int nblocks = (BB * SS * SS) / 64;   // 4096
    points_render_kernel<<<dim3(nblocks), dim3(256), 0, stream>>>(
        features, idx, zbuf, dist, out);
}

// Round 8
// 90.732 us; speedup vs baseline: 1.2108x; 1.2108x over previous
//
#include <hip/hip_runtime.h>

// PointsRenderer: B=4, N=100000, F=64, S=256, K=8, R=2/256
// out = (B, F+1, S, S) f32: channels 0..63 = composited features, 64 = depth.
//
// Final characterization (rounds 1-7): bound by the random 256B row-gather
// line path at ~3.6 TB/s effective (~9.5M 64B lines in ~92us ~= the measured
// ~98 G-line/s fabric ceiling). Measured nulls: VALU shape (51->8%), gather
// width x4, MLP/unroll, occupancy, nt on streams, fp16 table (net negative
// with per-call convert). Measured negative: nt on gathers (-20% -- L1/L2
// allocation on the gather path serves real hits; keep gathers cached).

#define BB 4
#define NN 100000
#define FF 64
#define SS 256
#define KK 8
#define BN (BB * NN)          // 400000
#define RR_INV 16384.0f       // 1 / (r*r),  r = 2*1.0/256

typedef float f32x4 __attribute__((ext_vector_type(4)));
typedef int   i32x4 __attribute__((ext_vector_type(4)));

__global__ __launch_bounds__(256)
void points_render_kernel(const float* __restrict__ features, // [BN][FF]
                          const int*   __restrict__ idx,      // [B][S][S][K] int32
                          const float* __restrict__ zbuf,     // [B][S][S][K]
                          const float* __restrict__ dist,     // [B][S][S][K]
                          float* __restrict__ out)            // [B][FF+1][S][S]
{
    // Block covers 64 consecutive x-pixels of one row (b, y).
    __shared__ float tile[64][FF + 1];      // [local x][channel], stride 65
    __shared__ float s_contrib[64][KK];     // per-(pixel,k) compositing weight
    __shared__ int   s_off[64][KK];         // pre-scaled gather offset si*FF

    const int tid  = threadIdx.x;
    const int wave = tid >> 6;
    const int lane = tid & 63;

    const int blk = blockIdx.x;             // 4096 blocks
    const int xb  = blk & 3;
    const int y   = (blk >> 2) & (SS - 1);
    const int b   = blk >> 10;
    const int x0  = xb * 64;

    const long long pixbase = (((long long)b * SS + y) * SS + x0);

    // ---- Phase A: all 4 waves; lanes 0..15 of wave w own pixels w*16.. ----
    if (lane < 16) {
        const int pix = wave * 16 + lane;
        const long long p = pixbase + pix;
        const f32x4* d4 = (const f32x4*)(dist + p * KK);
        const f32x4* z4 = (const f32x4*)(zbuf + p * KK);
        const i32x4* i4 = (const i32x4*)(idx  + p * KK);
        const f32x4 da = __builtin_nontemporal_load(d4);
        const f32x4 db = __builtin_nontemporal_load(d4 + 1);
        const f32x4 za = __builtin_nontemporal_load(z4);
        const f32x4 zb = __builtin_nontemporal_load(z4 + 1);
        const i32x4 ia = __builtin_nontemporal_load(i4);
        const i32x4 ib = __builtin_nontemporal_load(i4 + 1);

        float dd[KK] = {da.x, da.y, da.z, da.w, db.x, db.y, db.z, db.w};
        float zz[KK] = {za.x, za.y, za.z, za.w, zb.x, zb.y, zb.z, zb.w};
        int   ii[KK] = {ia.x, ia.y, ia.z, ia.w, ib.x, ib.y, ib.z, ib.w};

        float trans = 1.0f, wsum = 0.0f, depth = 0.0f;
        #pragma unroll
        for (int k = 0; k < KK; ++k) {
            float a  = __expf(-fmaxf(dd[k] * RR_INV, 0.0f));
            float we = fminf(a, 0.99f);
            if (ii[k] < 0) we = 0.0f;                 // valid mask
            s_contrib[pix][k] = we * trans;
            trans *= (1.0f - we);
            wsum  += we;
            depth += zz[k] * we;

            int si = ii[k];
            si = si < 0 ? 0 : (si > BN - 1 ? BN - 1 : si);  // safe_idx
            s_off[pix][k] = si * FF;
        }
        tile[pix][FF] = depth / fmaxf(wsum, 1e-9f);
    }
    __syncthreads();

    // ---- Phase B: gather + FMA. Wave w owns pixels [w*16, w*16+16).
    //      lane = feature index; each load is one full 256B row burst,
    //      CACHED (L1/L2 hits on re-drawn rows are worth ~20us). ----
    const float* fl = features + lane;     // per-lane column base

    #pragma unroll 4
    for (int i = 0; i < 16; ++i) {
        const int xl = wave * 16 + i;
        // wave-uniform LDS broadcasts (no conflicts)
        const float4 c0 = *(const float4*)&s_contrib[xl][0];
        const float4 c1 = *(const float4*)&s_contrib[xl][4];
        const int4   o0 = *(const int4*)&s_off[xl][0];
        const int4   o1 = *(const int4*)&s_off[xl][4];

        // 8 coalesced 256B gathers
        const float g0 = fl[o0.x], g1 = fl[o0.y], g2 = fl[o0.z], g3 = fl[o0.w];
        const float g4 = fl[o1.x], g5 = fl[o1.y], g6 = fl[o1.z], g7 = fl[o1.w];

        tile[xl][lane] = g0*c0.x + g1*c0.y + g2*c0.z + g3*c0.w
                       + g4*c1.x + g5*c1.y + g6*c1.z + g7*c1.w;
    }
    __syncthreads();

    // ---- Write 64 x 65 floats: contiguous 256B channel segments ----
    float* outb = out + (long long)b * (FF + 1) * SS * SS + (long long)y * SS + x0;
    for (int j = tid; j < 64 * (FF + 1); j += 256) {
        const int c  = j >> 6;
        const int xl = j & 63;
        __builtin_nontemporal_store(tile[xl][c], &outb[(long long)c * (SS * SS) + xl]);
    }
}

extern "C" void kernel_launch(void* const* d_in, const int* in_sizes, int n_in,
                              void* d_out, int out_size, void* d_ws, size_t ws_size,
                              hipStream_t stream) {
    const float* features = (const float*)d_in[0];
    const int*   idx      = (const int*)d_in[1];
    const float* zbuf     = (const float*)d_in[2];
    const float* dist     = (const float*)d_in[3];
    float* out = (float*)d_out;

    const int nblocks = (BB * SS * SS) / 64;   // 4096
    points_render_kernel<<<dim3(nblocks), dim3(256), 0, stream>>>(
        features, idx, zbuf, dist, out);
}